// Round 18
// baseline (331.108 us; speedup 1.0000x reference)
//
#include <hip/hip_runtime.h>
#include <stdint.h>

// Segment layout (elements in each battle row of 10451 floats):
//  player 9 @0 | status 86 @9 | pinfo 8 @95 | 13 x card(740) @103 | potions 43 @9723
//  | relics 180 @9766 | 5 x monster(101) @9946
// Output row (542 floats): player4 @0 | status16 @4 | pinfo2 @20 | cards 13*32 @22
//  | potions8 @438 | relics16 @446 | monsters 5*16 @462
//
// R17 (297us) + 2-PHASE CARD STAGE: stage k-half-0 (slice-wise into [13][388],
// stride == 740 mod 32 -> same conflict-free class) -> vmcnt(0)+barrier ->
// ISSUE k-half-1's DMA -> compute half-0 + smalls while half-1 streams ->
// vmcnt(0)+barrier -> compute half-1 -> wred/orow (R17 epilogue). R15's NaN
// proved hipcc inserts NO vmcnt before ds_reads after global_load_lds, so
// the explicit per-wave vmcnt(0)+barrier is both necessary AND sufficient --
// and DMA issued between barriers stays in flight through compute.

typedef __attribute__((ext_vector_type(8))) short short8;
typedef __attribute__((ext_vector_type(4))) float f32x4;

__device__ inline unsigned short f2bf(float f) {
  union { float f; uint32_t u; } v; v.f = f;
  uint32_t r = v.u + 0x7FFFu + ((v.u >> 16) & 1u);   // round-to-nearest-even
  return (unsigned short)(r >> 16);
}

// packed bf16 pair via the HW converter (RNE), 1 VALU op for 2 elements
__device__ inline uint32_t cvt2(float lo, float hi) {
  uint32_t r;
  asm("v_cvt_pk_bf16_f32 %0, %1, %2" : "=v"(r) : "v"(lo), "v"(hi));
  return r;
}

union bfrag { short8 s; uint32_t u[4]; };

__device__ inline short8 mk_frag(f32x4 lo, f32x4 hi) {
  bfrag f;
  f.u[0] = cvt2(lo[0], lo[1]);
  f.u[1] = cvt2(lo[2], lo[3]);
  f.u[2] = cvt2(hi[0], hi[1]);
  f.u[3] = cvt2(hi[2], hi[3]);
  return f.s;
}

__device__ inline void gload_dw(const float* g, float* lds) {
  __builtin_amdgcn_global_load_lds(
      (const __attribute__((address_space(1))) void*)g,
      (__attribute__((address_space(3))) void*)lds, 4, 0, 0);
}

// W -> fragment-interleaved bf16. 41 chunks x 512 dwords:
//  chunk 0..23 card | 24..26 status | 27..28 potions | 29 player | 30 pinfo
//  | 31..34 monster | 35..40 relics.
// dword idx = chunk*512 + wn*256 + kg*64 + rl*4 + d holds W[n][k],W[n][k+1]
// with n = wn*16+rl, k = (chunk-cbase)*32 + kg*8 + d*2; zero outside NOUT/K.
__global__ __launch_bounds__(256) void pack_w(
    const float* __restrict__ Wp, const float* __restrict__ Ws,
    const float* __restrict__ Wpi, const float* __restrict__ Wc,
    const float* __restrict__ Wpo, const float* __restrict__ Wr,
    const float* __restrict__ Wm, uint32_t* __restrict__ wout) {
  int el = blockIdx.x * 256 + threadIdx.x;
  if (el >= 20992) return;
  int d  = el & 3;
  int rl = (el >> 2) & 15;
  int kg = (el >> 6) & 3;
  int wn = (el >> 8) & 1;
  int chunk = el >> 9;
  const float* w; int K, NOUT, cbase;
  if (chunk < 24)      { w = Wc;  K = 740; NOUT = 32; cbase = 0; }
  else if (chunk < 27) { w = Ws;  K = 86;  NOUT = 16; cbase = 24; }
  else if (chunk < 29) { w = Wpo; K = 43;  NOUT = 8;  cbase = 27; }
  else if (chunk < 30) { w = Wp;  K = 9;   NOUT = 4;  cbase = 29; }
  else if (chunk < 31) { w = Wpi; K = 8;   NOUT = 2;  cbase = 30; }
  else if (chunk < 35) { w = Wm;  K = 101; NOUT = 16; cbase = 31; }
  else                 { w = Wr;  K = 180; NOUT = 16; cbase = 35; }
  int n = wn * 16 + rl;
  int k = (chunk - cbase) * 32 + kg * 8 + d * 2;
  float v0 = (n < NOUT && k     < K) ? w[n * K + k]     : 0.0f;
  float v1 = (n < NOUT && k + 1 < K) ? w[n * K + k + 1] : 0.0f;
  wout[el] = (uint32_t)f2bf(v0) | ((uint32_t)f2bf(v1) << 16);
}

__global__ __launch_bounds__(256, 3) void seg_gemm(
    const float* __restrict__ battle,
    const uint32_t* __restrict__ wpack2,
    float* __restrict__ out)
{
  // LDS floats: ph0[0..5044) | ph1[5044..10088) | smalls[10088..10968)
  //             | wred[10968..11480) | orow[11480..12024)   (48.1 KB)
  __shared__ float shm[12024];
  const int b    = blockIdx.x;          // battle row
  const int t    = threadIdx.x;
  const int lane = t & 63;
  const int wv   = t >> 6;
  const int rl   = lane & 15;
  const int kg   = lane >> 4;
  const int wn   = wv & 1;              // card n-half
  const int wk   = wv >> 1;             // card chunk-half within phase

  const uint32_t row = (uint32_t)b * 10451u;

  // slice-wise card stage of k-half p: slice s (0..12), part j (0..5);
  // wave w handles slices s%4==w. Per-instruction dst is linear (base+lane*4).
  #define STAGE_HALF(P, BUF) do {                                              \
    for (int s = wv; s < 13; s += 4)                                           \
      _Pragma("unroll")                                                        \
      for (int j = 0; j < 6; ++j)                                              \
        gload_dw(battle + row + 103u +                                         \
                   (uint32_t)(s * 740 + (P) * 384 + j * 64 + lane),            \
                 &shm[(BUF) + s * 388 + j * 64 + lane]);                       \
  } while (0)

  STAGE_HALF(0, 0);
  // ---- smalls stage (drained with phase 0) ----
  #pragma unroll
  for (int r = 0; r < 4; ++r) {
    const int s = r * 256 + t;
    if (s < 880) {
      int src;
      if (s < 12)        src = s;                 // player (+gap: garbage x0)
      else if (s < 100)  src = 9 + (s - 12);      // status (+tail x0)
      else if (s < 112)  src = 95 + (s - 100);    // pinfo
      else if (s < 156)  src = 9723 + (s - 112);  // potions
      else if (s < 336)  src = 9766 + (s - 156);  // relics
      else if (s < 856) {                         // monster, rows padded to 104
        int sub = (s - 336) / 104;
        int kk  = (s - 336) - sub * 104;
        src = 9946 + sub * 101 + ((kk > 100) ? 100 : kk);
      } else src = 0;                             // pad (finite x0)
      gload_dw(battle + row + (uint32_t)src, &shm[10088 + s]);
    }
  }
  asm volatile("s_waitcnt vmcnt(0)" ::: "memory");
  __syncthreads();                       // phase-0 + smalls data ready

  STAGE_HALF(1, 5044);                   // in flight through phase-0 compute

  const uint32_t abase = (rl < 13) ? (uint32_t)(rl * 388) : 0u;
  float* wred = &shm[10968];
  float* orow = &shm[11480];

  f32x4 acc = {0.f, 0.f, 0.f, 0.f};
  // ---- card compute, phase 0: chunks 0..11, this wave takes 6 ----
  #pragma unroll
  for (int si = 0; si < 6; ++si) {
    const int cs = wk * 6 + si;                  // global chunk, k = cs*32+kg*8
    const float* ap = shm + abase + (uint32_t)(cs * 32 + kg * 8);
    f32x4 lo = *(const f32x4*)ap;
    f32x4 hi = *(const f32x4*)(ap + 4);
    short8 aa = mk_frag(lo, hi);
    short8 wf = *(const short8*)(wpack2 + (uint32_t)(cs * 512 + wn * 256 + kg * 64 + rl * 4));
    acc = __builtin_amdgcn_mfma_f32_16x16x32_bf16(aa, wf, acc, 0, 0, 0);
  }

  // ---- small segments (waves 0-2) -> orow, also inside the overlap window ----
  #define DO_SEG(CBASE, NCH, SBOFF, STRIDE, M, NOUTS, OOFF) do {               \
    f32x4 sacc = {0.f, 0.f, 0.f, 0.f};                                         \
    _Pragma("unroll")                                                          \
    for (int c = 0; c < (NCH); ++c) {                                          \
      const uint32_t ab = 10088u + (SBOFF) +                                   \
                          ((rl < (M)) ? (uint32_t)(rl * (STRIDE)) : 0u);       \
      const float* ap = shm + ab + (uint32_t)(c * 32 + kg * 8);                \
      f32x4 lo = *(const f32x4*)ap;                                            \
      f32x4 hi = *(const f32x4*)(ap + 4);                                      \
      short8 aa = mk_frag(lo, hi);                                             \
      short8 wf = *(const short8*)(wpack2 +                                    \
                    (uint32_t)(((CBASE) + c) * 512 + kg * 64 + rl * 4));       \
      sacc = __builtin_amdgcn_mfma_f32_16x16x32_bf16(aa, wf, sacc, 0, 0, 0);   \
    }                                                                          \
    _Pragma("unroll")                                                          \
    for (int q = 0; q < 4; ++q) {                                              \
      const int rowq = kg * 4 + q;                                             \
      if (rowq < (M) && rl < (NOUTS))                                          \
        orow[(OOFF) + rowq * (NOUTS) + rl] = sacc[q];                          \
    }                                                                          \
  } while (0)

  if (wv == 0) {
    DO_SEG(24, 3, 12u,  0, 1, 16, 4);     // status
    DO_SEG(27, 2, 112u, 0, 1, 8,  438);   // potions
    DO_SEG(29, 1, 0u,   0, 1, 4,  0);     // player
    DO_SEG(30, 1, 100u, 0, 1, 2,  20);    // pinfo
  } else if (wv == 1) {
    DO_SEG(31, 4, 336u, 104, 5, 16, 462); // monster
  } else if (wv == 2) {
    DO_SEG(35, 6, 156u, 0, 1, 16, 446);   // relics
  }
  #undef DO_SEG

  asm volatile("s_waitcnt vmcnt(0)" ::: "memory");
  __syncthreads();                       // phase-1 data ready

  // ---- card compute, phase 1: chunks 12..23 from buf1 ----
  #pragma unroll
  for (int si = 0; si < 6; ++si) {
    const int cs = 12 + wk * 6 + si;
    const float* ap = shm + 5044u + abase + (uint32_t)((cs - 12) * 32 + kg * 8);
    f32x4 lo = *(const f32x4*)ap;
    f32x4 hi = *(const f32x4*)(ap + 4);
    short8 aa = mk_frag(lo, hi);
    short8 wf = *(const short8*)(wpack2 + (uint32_t)(cs * 512 + wn * 256 + kg * 64 + rl * 4));
    acc = __builtin_amdgcn_mfma_f32_16x16x32_bf16(aa, wf, acc, 0, 0, 0);
  }

  // ---- wred reduce (wk pairs), as R17 ----
  if (wk == 1) {
    #pragma unroll
    for (int q = 0; q < 4; ++q)
      wred[wn * 256 + (kg * 4 + q) * 16 + rl] = acc[q];
  }
  __syncthreads();
  if (wk == 0) {
    #pragma unroll
    for (int q = 0; q < 4; ++q) {
      const int sub = kg * 4 + q;       // C/D: row = kg*4+q, col = rl
      float v = acc[q] + wred[wn * 256 + (kg * 4 + q) * 16 + rl];
      if (sub < 13)
        orow[22 + sub * 32 + wn * 16 + rl] = v;
    }
  }

  // ---- coalesced row store ----
  __syncthreads();
  const uint32_t ob0 = (uint32_t)b * 542u;
  #pragma unroll
  for (int i = t; i < 542; i += 256)
    out[ob0 + (uint32_t)i] = orow[i];
}

extern "C" void kernel_launch(void* const* d_in, const int* in_sizes, int n_in,
                              void* d_out, int out_size, void* d_ws, size_t ws_size,
                              hipStream_t stream) {
  const float* battle   = (const float*)d_in[0];
  const float* Wplayer  = (const float*)d_in[1];
  const float* Wstatus  = (const float*)d_in[2];
  const float* Wpinfo   = (const float*)d_in[3];
  const float* Wcard    = (const float*)d_in[4];
  const float* Wpotions = (const float*)d_in[5];
  const float* Wrelics  = (const float*)d_in[6];
  const float* Wmonster = (const float*)d_in[7];
  float* out = (float*)d_out;

  uint32_t* wpack2 = (uint32_t*)d_ws;    // 41*512 dwords = 84 KB packed W

  hipLaunchKernelGGL(pack_w, dim3(82), dim3(256), 0, stream,
                     Wplayer, Wstatus, Wpinfo, Wcard, Wpotions, Wrelics,
                     Wmonster, wpack2);
  hipLaunchKernelGGL(seg_gemm, dim3(32768), dim3(256), 0, stream,
                     battle, (const uint32_t*)wpack2, out);
}

// Round 19
// 296.876 us; speedup vs baseline: 1.1153x; 1.1153x over previous
//
#include <hip/hip_runtime.h>
#include <stdint.h>

// Segment layout (elements in each battle row of 10451 floats):
//  player 9 @0 | status 86 @9 | pinfo 8 @95 | 13 x card(740) @103 | potions 43 @9723
//  | relics 180 @9766 | 5 x monster(101) @9946
// Output row (542 floats): player4 @0 | status16 @4 | pinfo2 @20 | cards 13*32 @22
//  | potions8 @438 | relics16 @446 | monsters 5*16 @462
//
// FINAL (R17 structure, best measured 297us = 77% of copy ceiling):
// unified one-row blocks; card region staged as one contiguous span (no
// k-windows -> no sector overfetch); smalls staged via per-lane source map;
// cvt_pk bf16 fragments; frag-interleaved bf16 W (packed once per launch);
// smalls computed as extra MFMA chunks on waves 0-2; whole 542-float output
// row gathered in LDS and stored as contiguous coalesced bursts.
// Scheduling/overlap variants all measured worse: R3/R6/R8/R12/R13/R16/R18.

typedef __attribute__((ext_vector_type(8))) short short8;
typedef __attribute__((ext_vector_type(4))) float f32x4;

__device__ inline unsigned short f2bf(float f) {
  union { float f; uint32_t u; } v; v.f = f;
  uint32_t r = v.u + 0x7FFFu + ((v.u >> 16) & 1u);   // round-to-nearest-even
  return (unsigned short)(r >> 16);
}

// packed bf16 pair via the HW converter (RNE), 1 VALU op for 2 elements
__device__ inline uint32_t cvt2(float lo, float hi) {
  uint32_t r;
  asm("v_cvt_pk_bf16_f32 %0, %1, %2" : "=v"(r) : "v"(lo), "v"(hi));
  return r;
}

union bfrag { short8 s; uint32_t u[4]; };

__device__ inline short8 mk_frag(f32x4 lo, f32x4 hi) {
  bfrag f;
  f.u[0] = cvt2(lo[0], lo[1]);
  f.u[1] = cvt2(lo[2], lo[3]);
  f.u[2] = cvt2(hi[0], hi[1]);
  f.u[3] = cvt2(hi[2], hi[3]);
  return f.s;
}

__device__ inline void gload_dw(const float* g, float* lds) {
  __builtin_amdgcn_global_load_lds(
      (const __attribute__((address_space(1))) void*)g,
      (__attribute__((address_space(3))) void*)lds, 4, 0, 0);
}

// W -> fragment-interleaved bf16. 41 chunks x 512 dwords:
//  chunk 0..23 card | 24..26 status | 27..28 potions | 29 player | 30 pinfo
//  | 31..34 monster | 35..40 relics.
// dword idx = chunk*512 + wn*256 + kg*64 + rl*4 + d holds W[n][k],W[n][k+1]
// with n = wn*16+rl, k = (chunk-cbase)*32 + kg*8 + d*2; zero outside NOUT/K.
__global__ __launch_bounds__(256) void pack_w(
    const float* __restrict__ Wp, const float* __restrict__ Ws,
    const float* __restrict__ Wpi, const float* __restrict__ Wc,
    const float* __restrict__ Wpo, const float* __restrict__ Wr,
    const float* __restrict__ Wm, uint32_t* __restrict__ wout) {
  int el = blockIdx.x * 256 + threadIdx.x;
  if (el >= 20992) return;
  int d  = el & 3;
  int rl = (el >> 2) & 15;
  int kg = (el >> 6) & 3;
  int wn = (el >> 8) & 1;
  int chunk = el >> 9;
  const float* w; int K, NOUT, cbase;
  if (chunk < 24)      { w = Wc;  K = 740; NOUT = 32; cbase = 0; }
  else if (chunk < 27) { w = Ws;  K = 86;  NOUT = 16; cbase = 24; }
  else if (chunk < 29) { w = Wpo; K = 43;  NOUT = 8;  cbase = 27; }
  else if (chunk < 30) { w = Wp;  K = 9;   NOUT = 4;  cbase = 29; }
  else if (chunk < 31) { w = Wpi; K = 8;   NOUT = 2;  cbase = 30; }
  else if (chunk < 35) { w = Wm;  K = 101; NOUT = 16; cbase = 31; }
  else                 { w = Wr;  K = 180; NOUT = 16; cbase = 35; }
  int n = wn * 16 + rl;
  int k = (chunk - cbase) * 32 + kg * 8 + d * 2;
  float v0 = (n < NOUT && k     < K) ? w[n * K + k]     : 0.0f;
  float v1 = (n < NOUT && k + 1 < K) ? w[n * K + k + 1] : 0.0f;
  wout[el] = (uint32_t)f2bf(v0) | ((uint32_t)f2bf(v1) << 16);
}

__global__ __launch_bounds__(256, 3) void seg_gemm(
    const float* __restrict__ battle,
    const uint32_t* __restrict__ wpack2,
    float* __restrict__ out)
{
  // LDS: card[0..9728) | smalls[9728..10608) | wred[10608..11120) | orow[11120..11664)
  __shared__ float shm[11664];
  const int b    = blockIdx.x;          // battle row
  const int t    = threadIdx.x;
  const int lane = t & 63;
  const int wv   = t >> 6;
  const int rl   = lane & 15;
  const int kg   = lane >> 4;
  const int wn   = wv & 1;              // card n-half
  const int wk   = wv >> 1;             // card K-half

  const uint32_t row = (uint32_t)b * 10451u;

  // ---- stage card region [103, 9831) -> shm[0..9728) ----
  #pragma unroll
  for (int r = 0; r < 38; ++r)
    gload_dw(battle + row + 103u + (uint32_t)(r * 256 + t), &shm[r * 256 + t]);

  // ---- stage smalls -> shm[9728..10608): per-lane source map, linear dest --
  // layout: player@0(9) status@12(86) pinfo@100(8) potions@112(43)
  // relics@156(180) monster@336(5 x stride 104)
  #pragma unroll
  for (int r = 0; r < 4; ++r) {
    const int s = r * 256 + t;
    if (s < 880) {
      int src;
      if (s < 12)        src = s;                 // player (+gap: garbage x0)
      else if (s < 100)  src = 9 + (s - 12);      // status (+tail x0)
      else if (s < 112)  src = 95 + (s - 100);    // pinfo
      else if (s < 156)  src = 9723 + (s - 112);  // potions
      else if (s < 336)  src = 9766 + (s - 156);  // relics
      else if (s < 856) {                         // monster, rows padded to 104
        int sub = (s - 336) / 104;
        int kk  = (s - 336) - sub * 104;
        src = 9946 + sub * 101 + ((kk > 100) ? 100 : kk);
      } else src = 0;                             // pad (finite x0)
      gload_dw(battle + row + (uint32_t)src, &shm[9728 + s]);
    }
  }
  __syncthreads();   // drains vmcnt(0); LDS read-only afterwards

  // ======================= card compute (R8 structure) =======================
  const uint32_t abase = (rl < 13) ? (uint32_t)(rl * 740) : 0u;
  float* wred = &shm[10608];
  float* orow = &shm[11120];

  f32x4 acc = {0.f, 0.f, 0.f, 0.f};
  #pragma unroll
  for (int si = 0; si < 12; ++si) {
    const int cs = wk * 12 + si;        // k = cs*32 + kg*8 (+0..7)
    const float* ap = shm + abase + (uint32_t)(cs * 32 + kg * 8);
    f32x4 lo = *(const f32x4*)ap;
    f32x4 hi = *(const f32x4*)(ap + 4);
    short8 aa = mk_frag(lo, hi);
    short8 wf = *(const short8*)(wpack2 + (uint32_t)(cs * 512 + wn * 256 + kg * 64 + rl * 4));
    acc = __builtin_amdgcn_mfma_f32_16x16x32_bf16(aa, wf, acc, 0, 0, 0);
  }

  if (wk == 1) {
    #pragma unroll
    for (int q = 0; q < 4; ++q)
      wred[wn * 256 + (kg * 4 + q) * 16 + rl] = acc[q];
  }
  __syncthreads();

  if (wk == 0) {
    #pragma unroll
    for (int q = 0; q < 4; ++q) {
      const int sub = kg * 4 + q;       // C/D: row = kg*4+q, col = rl
      float v = acc[q] + wred[wn * 256 + (kg * 4 + q) * 16 + rl];
      if (sub < 13)
        orow[22 + sub * 32 + wn * 16 + rl] = v;
    }
  }

  // ======================= small segments (waves 0-2) -> orow =======================
  #define DO_SEG(CBASE, NCH, SBOFF, STRIDE, M, NOUTS, OOFF) do {               \
    f32x4 sacc = {0.f, 0.f, 0.f, 0.f};                                         \
    _Pragma("unroll")                                                          \
    for (int c = 0; c < (NCH); ++c) {                                          \
      const uint32_t ab = 9728u + (SBOFF) +                                    \
                          ((rl < (M)) ? (uint32_t)(rl * (STRIDE)) : 0u);       \
      const float* ap = shm + ab + (uint32_t)(c * 32 + kg * 8);                \
      f32x4 lo = *(const f32x4*)ap;                                            \
      f32x4 hi = *(const f32x4*)(ap + 4);                                      \
      short8 aa = mk_frag(lo, hi);                                             \
      short8 wf = *(const short8*)(wpack2 +                                    \
                    (uint32_t)(((CBASE) + c) * 512 + kg * 64 + rl * 4));       \
      sacc = __builtin_amdgcn_mfma_f32_16x16x32_bf16(aa, wf, sacc, 0, 0, 0);   \
    }                                                                          \
    _Pragma("unroll")                                                          \
    for (int q = 0; q < 4; ++q) {                                              \
      const int rowq = kg * 4 + q;                                             \
      if (rowq < (M) && rl < (NOUTS))                                          \
        orow[(OOFF) + rowq * (NOUTS) + rl] = sacc[q];                          \
    }                                                                          \
  } while (0)

  if (wv == 0) {
    DO_SEG(24, 3, 12u,  0, 1, 16, 4);     // status
    DO_SEG(27, 2, 112u, 0, 1, 8,  438);   // potions
    DO_SEG(29, 1, 0u,   0, 1, 4,  0);     // player
    DO_SEG(30, 1, 100u, 0, 1, 2,  20);    // pinfo
  } else if (wv == 1) {
    DO_SEG(31, 4, 336u, 104, 5, 16, 462); // monster
  } else if (wv == 2) {
    DO_SEG(35, 6, 156u, 0, 1, 16, 446);   // relics
  }
  #undef DO_SEG

  // ======================= coalesced row store =======================
  __syncthreads();
  const uint32_t ob0 = (uint32_t)b * 542u;
  #pragma unroll
  for (int i = t; i < 542; i += 256)
    out[ob0 + (uint32_t)i] = orow[i];
}

extern "C" void kernel_launch(void* const* d_in, const int* in_sizes, int n_in,
                              void* d_out, int out_size, void* d_ws, size_t ws_size,
                              hipStream_t stream) {
  const float* battle   = (const float*)d_in[0];
  const float* Wplayer  = (const float*)d_in[1];
  const float* Wstatus  = (const float*)d_in[2];
  const float* Wpinfo   = (const float*)d_in[3];
  const float* Wcard    = (const float*)d_in[4];
  const float* Wpotions = (const float*)d_in[5];
  const float* Wrelics  = (const float*)d_in[6];
  const float* Wmonster = (const float*)d_in[7];
  float* out = (float*)d_out;

  uint32_t* wpack2 = (uint32_t*)d_ws;    // 41*512 dwords = 84 KB packed W

  hipLaunchKernelGGL(pack_w, dim3(82), dim3(256), 0, stream,
                     Wplayer, Wstatus, Wpinfo, Wcard, Wpotions, Wrelics,
                     Wmonster, wpack2);
  hipLaunchKernelGGL(seg_gemm, dim3(32768), dim3(256), 0, stream,
                     battle, (const uint32_t*)wpack2, out);
}